// Round 2
// baseline (97.071 us; speedup 1.0000x reference)
//
#include <hip/hip_runtime.h>
#include <hip/hip_bf16.h>
#include <math.h>

#define BS 8192
#define D 128
#define NROWS 16384               // 2*BS
#define BM 128                    // rows per block
#define BN 128                    // cols per tile
#define COLS_PER_BLOCK 1024
#define NTILES (COLS_PER_BLOCK / BN)      // 8
#define NSPLIT (NROWS / COLS_PER_BLOCK)   // 16
#define NPART (NSPLIT * 2)                // 32 partial buffers (wc split)

typedef __bf16 bf16x8 __attribute__((ext_vector_type(8)));
typedef float f32x4 __attribute__((ext_vector_type(4)));

#define SQRT_LOG2E 1.2011224087864498f
#define LN2F 0.6931471805599453f

#if __has_builtin(__builtin_amdgcn_exp2f)
#define EXP2F(x) __builtin_amdgcn_exp2f(x)
#else
#define EXP2F(x) exp2f(x)
#endif

// Kernel 1: row norms + pre-scaled bf16 conversion.
// cat rows [0,8192) = noise, [8192,16384) = f. Each row scaled by sqrt(log2e)/||row||
// so the MFMA dot directly yields cos_sim * log2(e) -> epilogue is a bare exp2.
__global__ __launch_bounds__(256) void nrm_cvt(const float* __restrict__ f,
                                               const float* __restrict__ noise,
                                               __hip_bfloat16* __restrict__ catb) {
  const int lane = threadIdx.x & 63;
  const int wv = threadIdx.x >> 6;
  const int row = blockIdx.x * 4 + wv;
  const float* src = (row < BS) ? (noise + (size_t)row * D) : (f + (size_t)(row - BS) * D);
  float2 v = ((const float2*)src)[lane];
  float ss = v.x * v.x + v.y * v.y;
#pragma unroll
  for (int m = 1; m <= 32; m <<= 1) ss += __shfl_xor(ss, m, 64);
  float s = SQRT_LOG2E / sqrtf(ss);
  float2 sv;
  sv.x = v.x * s;
  sv.y = v.y * s;
  __hip_bfloat162 b2 = __float22bfloat162_rn(sv);
  ((__hip_bfloat162*)(catb + (size_t)row * D))[lane] = b2;
}

// Kernel 2: fused GEMM + exp2 + row-sum, NO LDS (cat is L2-resident), no barriers.
// Block: 4 waves (2 row x 2 col). Wave owns 64 rows x 64 cols per tile, processed
// in two 32-col half-steps so acc stays at 32 VGPRs (target 3 waves/SIMD).
__global__ __launch_bounds__(256, 3) void infonce_main(
    const __hip_bfloat16* __restrict__ catb,
    float* __restrict__ ws_neg, float* __restrict__ ws_pos) {
  const int tid = threadIdx.x;
  const int lane = tid & 63;
  const int w = tid >> 6;
  const int wr = w >> 1, wc = w & 1;
  const int l15 = lane & 15, l4 = lane >> 4;
  const int nb = blockIdx.x, mb = blockIdx.y;
  const int mrow0 = mb * BM;
  const int col0 = nb * COLS_PER_BLOCK;
  const char* catbytes = (const char*)catb;

  // A fragments: this wave's 64 f-rows, all of K=128, in registers (64 VGPRs).
  bf16x8 a[4][4];
  {
    const char* fb = catbytes + (size_t)BS * 256;
#pragma unroll
    for (int rf = 0; rf < 4; rf++) {
      const char* p = fb + (size_t)(mrow0 + wr * 64 + rf * 16 + l15) * 256 + l4 * 16;
#pragma unroll
      for (int kk = 0; kk < 4; kk++) a[rf][kk] = *(const bf16x8*)(p + kk * 64);
    }
  }

  float rowsum[16];
#pragma unroll
  for (int i = 0; i < 16; i++) rowsum[i] = 0.f;

  // per-lane B base: this lane supplies col (.. + l15), k-chunk l4
  const char* bbase = catbytes + (size_t)(col0 + wc * 64 + l15) * 256 + l4 * 16;
  const int growbase = mrow0 + wr * 64;

#pragma unroll 2
  for (int t = 0; t < NTILES; t++) {
#pragma unroll
    for (int h = 0; h < 2; h++) {
      const char* bb = bbase + (size_t)(t * BN + h * 32) * 256;
      f32x4 acc[4][2];
      const f32x4 z = {0.f, 0.f, 0.f, 0.f};
#pragma unroll
      for (int rf = 0; rf < 4; rf++) {
        acc[rf][0] = z;
        acc[rf][1] = z;
      }
#pragma unroll
      for (int kk = 0; kk < 4; kk++) {
        bf16x8 b0 = *(const bf16x8*)(bb + kk * 64);
        bf16x8 b1 = *(const bf16x8*)(bb + 4096 + kk * 64);
#pragma unroll
        for (int rf = 0; rf < 4; rf++) {
          acc[rf][0] = __builtin_amdgcn_mfma_f32_16x16x32_bf16(a[rf][kk], b0, acc[rf][0], 0, 0, 0);
          acc[rf][1] = __builtin_amdgcn_mfma_f32_16x16x32_bf16(a[rf][kk], b1, acc[rf][1], 0, 0, 0);
        }
      }

      // epilogue: acc holds sim*log2e. exp2 + row-sum accumulate.
      const int gch = col0 + t * BN + wc * 64 + h * 32;  // half's base col
      const bool dPos = (gch >> 7) == (mrow0 >> 7);           // cols == f-row ids
      const bool dSelf = (gch >> 7) == ((mrow0 + BS) >> 7);   // cols == i+bs
      if (!dPos && !dSelf) {
#pragma unroll
        for (int rf = 0; rf < 4; rf++)
#pragma unroll
          for (int cf = 0; cf < 2; cf++)
#pragma unroll
            for (int r = 0; r < 4; r++) rowsum[rf * 4 + r] += EXP2F(acc[rf][cf][r]);
      } else {
#pragma unroll
        for (int rf = 0; rf < 4; rf++)
#pragma unroll
          for (int cf = 0; cf < 2; cf++)
#pragma unroll
            for (int r = 0; r < 4; r++) {
              const int grow = growbase + rf * 16 + l4 * 4 + r;
              const int gcol = gch + cf * 16 + l15;
              const float v = acc[rf][cf][r];
              const bool ex = dPos ? (gcol == grow) : (gcol == grow + BS);
              if (dPos && gcol == grow) ws_pos[grow] = v;  // sim_pos * log2e
              rowsum[rf * 4 + r] += ex ? 0.f : EXP2F(v);
            }
      }
    }
  }

  // reduce across the 16 lanes (l15) sharing each row
#pragma unroll
  for (int s = 0; s < 16; s++) {
    float v = rowsum[s];
    v += __shfl_xor(v, 1, 64);
    v += __shfl_xor(v, 2, 64);
    v += __shfl_xor(v, 4, 64);
    v += __shfl_xor(v, 8, 64);
    rowsum[s] = v;
  }
  if (l15 == 0) {
    float* dst = ws_neg + (size_t)(nb * 2 + wc) * BS + mrow0 + wr * 64;
#pragma unroll
    for (int rf = 0; rf < 4; rf++)
#pragma unroll
      for (int r = 0; r < 4; r++) dst[rf * 16 + l4 * 4 + r] = rowsum[rf * 4 + r];
  }
}

// Kernel 3a: per-row loss, 32-block partial sums (coalesced partial reads).
__global__ __launch_bounds__(256) void finalize1(const float* __restrict__ ws_neg,
                                                 const float* __restrict__ ws_pos,
                                                 float* __restrict__ partial) {
  const int row = blockIdx.x * 256 + threadIdx.x;
  float neg = 0.f;
#pragma unroll
  for (int p = 0; p < NPART; p++) neg += ws_neg[(size_t)p * BS + row];
  // loss = log(neg_sum + eps) - sim_pos ; sim_pos = (sim*log2e)*ln2
  float local = logf(neg + 1e-6f) - ws_pos[row] * LN2F;
#pragma unroll
  for (int m = 1; m <= 32; m <<= 1) local += __shfl_xor(local, m, 64);
  __shared__ float red[4];
  if ((threadIdx.x & 63) == 0) red[threadIdx.x >> 6] = local;
  __syncthreads();
  if (threadIdx.x == 0) partial[blockIdx.x] = red[0] + red[1] + red[2] + red[3];
}

// Kernel 3b: final mean over the 32 block partials.
__global__ void finalize2(const float* __restrict__ partial, float* __restrict__ out) {
  float v = ((int)threadIdx.x < 32) ? partial[threadIdx.x] : 0.f;
#pragma unroll
  for (int m = 1; m <= 32; m <<= 1) v += __shfl_xor(v, m, 64);
  if (threadIdx.x == 0) out[0] = v * (1.f / BS);
}

extern "C" void kernel_launch(void* const* d_in, const int* in_sizes, int n_in,
                              void* d_out, int out_size, void* d_ws, size_t ws_size,
                              hipStream_t stream) {
  const float* f = (const float*)d_in[0];
  const float* noise = (const float*)d_in[1];
  char* ws = (char*)d_ws;
  __hip_bfloat16* catb = (__hip_bfloat16*)ws;                 // 4 MiB
  float* ws_pos = (float*)(ws + (size_t)NROWS * D * 2);       // 32 KiB
  float* ws_neg = ws_pos + BS;                                // 1 MiB
  float* partial = ws_neg + (size_t)NPART * BS;               // 128 B

  nrm_cvt<<<NROWS / 4, 256, 0, stream>>>(f, noise, catb);
  dim3 grid(NSPLIT, BS / BM);                                 // 16 x 64 = 1024 blocks
  infonce_main<<<grid, 256, 0, stream>>>(catb, ws_neg, ws_pos);
  finalize1<<<BS / 256, 256, 0, stream>>>(ws_neg, ws_pos, partial);
  finalize2<<<1, 64, 0, stream>>>(partial, (float*)d_out);
}

// Round 3
// 55.598 us; speedup vs baseline: 1.7459x; 1.7459x over previous
//
#include <hip/hip_runtime.h>
#include <hip/hip_bf16.h>
#include <math.h>

#define BS 8192
#define D 128
#define NROWS 16384               // 2*BS
#define BM 256                    // rows per block = 4 waves x 64
#define BN 64                     // cols per tile
#define COLS_PER_BLOCK 512
#define NTILES (COLS_PER_BLOCK / BN)      // 8
#define NSPLIT (NROWS / COLS_PER_BLOCK)   // 32
#define NPART NSPLIT                      // 32 partial buffers
#define TILE_B (BN * 256)                 // 16 KiB per LDS buffer

typedef __bf16 bf16x8 __attribute__((ext_vector_type(8)));
typedef float f32x4 __attribute__((ext_vector_type(4)));

#define SQRT_LOG2E 1.2011224087864498f
#define LN2F 0.6931471805599453f

#if __has_builtin(__builtin_amdgcn_exp2f)
#define EXP2F(x) __builtin_amdgcn_exp2f(x)
#else
#define EXP2F(x) exp2f(x)
#endif

__device__ __forceinline__ void gload_lds16(const void* g, void* l) {
  __builtin_amdgcn_global_load_lds(
      (const __attribute__((address_space(1))) void*)g,
      (__attribute__((address_space(3))) void*)l, 16, 0, 0);
}

// Kernel 1: row norms + pre-scaled bf16 conversion.
// cat rows [0,8192) = noise, [8192,16384) = f. Rows scaled by sqrt(log2e)/||row||
// so the MFMA dot yields cos_sim * log2(e) -> epilogue is a bare v_exp.
__global__ __launch_bounds__(256) void nrm_cvt(const float* __restrict__ f,
                                               const float* __restrict__ noise,
                                               __hip_bfloat16* __restrict__ catb) {
  const int lane = threadIdx.x & 63;
  const int wv = threadIdx.x >> 6;
  const int row = blockIdx.x * 4 + wv;
  const float* src = (row < BS) ? (noise + (size_t)row * D) : (f + (size_t)(row - BS) * D);
  float2 v = ((const float2*)src)[lane];
  float ss = v.x * v.x + v.y * v.y;
#pragma unroll
  for (int m = 1; m <= 32; m <<= 1) ss += __shfl_xor(ss, m, 64);
  float s = SQRT_LOG2E / sqrtf(ss);
  float2 sv;
  sv.x = v.x * s;
  sv.y = v.y * s;
  __hip_bfloat162 b2 = __float22bfloat162_rn(sv);
  ((__hip_bfloat162*)(catb + (size_t)row * D))[lane] = b2;
}

// Kernel 2: fused GEMM + exp2 + row-sum. 4 waves x 64 rows, shared 64-col B tiles.
// Triple-buffered LDS staged via global_load_lds (pre-swizzled source), counted
// vmcnt(4) + one raw s_barrier per tile -> no vmcnt(0) drain in the main loop.
__global__ __launch_bounds__(256, 3) void infonce_main(
    const __hip_bfloat16* __restrict__ catb,
    float* __restrict__ ws_neg, float* __restrict__ ws_pos) {
  __shared__ __align__(16) char lds[3 * TILE_B];  // 48 KiB
  const int tid = threadIdx.x;
  const int lane = tid & 63;
  const int w = tid >> 6;
  const int l15 = lane & 15, l4 = lane >> 4;
  const int nb = blockIdx.x, mb = blockIdx.y;
  const int mrow0 = mb * BM;
  const int col0 = nb * COLS_PER_BLOCK;
  const int growbase = mrow0 + w * 64;
  const char* catbytes = (const char*)catb;

  // staging constants: thread stages cols {i*16 + (tid>>4)}, 16B k-chunk (tid&15),
  // source pre-swizzled (XOR with (col&7)) so LDS dest stays linear.
  const int c16 = tid >> 4;
  const int kswz = ((tid & 15) ^ (c16 & 7)) << 4;
  const int ldst = c16 * 256 + (tid & 15) * 16;

  auto stage = [&](char* buf, int t) {
    const char* gb = catbytes + (size_t)(col0 + t * BN) * 256;
#pragma unroll
    for (int i = 0; i < 4; i++) {
      gload_lds16(gb + (i * 16 + c16) * 256 + kswz, buf + i * 4096 + ldst);
    }
  };

  // A fragments: this wave's 64 f-rows, all of K=128 (64 VGPRs).
  bf16x8 a[4][4];
  {
    const char* fb = catbytes + (size_t)BS * 256;
#pragma unroll
    for (int rf = 0; rf < 4; rf++) {
      const char* p = fb + (size_t)(growbase + rf * 16 + l15) * 256 + l4 * 16;
#pragma unroll
      for (int kk = 0; kk < 4; kk++) a[rf][kk] = *(const bf16x8*)(p + kk * 64);
    }
  }

  // ds_read swizzled k offsets (col&7 == l15&7 for all cf/h)
  int koff[4];
#pragma unroll
  for (int kk = 0; kk < 4; kk++) koff[kk] = ((kk * 64 + l4 * 16) ^ ((l15 & 7) << 4));

  float rowsum[16];
#pragma unroll
  for (int i = 0; i < 16; i++) rowsum[i] = 0.f;

  auto compute = [&](const char* buf, int colT) {
#pragma unroll
    for (int h = 0; h < 2; h++) {
      f32x4 acc[4][2];
      const f32x4 z = {0.f, 0.f, 0.f, 0.f};
#pragma unroll
      for (int rf = 0; rf < 4; rf++) {
        acc[rf][0] = z;
        acc[rf][1] = z;
      }
#pragma unroll
      for (int kk = 0; kk < 4; kk++) {
        bf16x8 b0 = *(const bf16x8*)(buf + (h * 32 + l15) * 256 + koff[kk]);
        bf16x8 b1 = *(const bf16x8*)(buf + (h * 32 + 16 + l15) * 256 + koff[kk]);
#pragma unroll
        for (int rf = 0; rf < 4; rf++) {
          acc[rf][0] = __builtin_amdgcn_mfma_f32_16x16x32_bf16(a[rf][kk], b0, acc[rf][0], 0, 0, 0);
          acc[rf][1] = __builtin_amdgcn_mfma_f32_16x16x32_bf16(a[rf][kk], b1, acc[rf][1], 0, 0, 0);
        }
      }
      // epilogue: acc = sim*log2e -> exp2, accumulate row sums, excise diagonals.
      const int gc0h = colT + h * 32;
      const bool dPos = ((gc0h >> 6) == (growbase >> 6));
      const bool dSelf = (gc0h >= BS) && (((gc0h - BS) >> 6) == (growbase >> 6));
      if (!dPos && !dSelf) {
#pragma unroll
        for (int rf = 0; rf < 4; rf++)
#pragma unroll
          for (int cf = 0; cf < 2; cf++)
#pragma unroll
            for (int r = 0; r < 4; r++) rowsum[rf * 4 + r] += EXP2F(acc[rf][cf][r]);
      } else {
#pragma unroll
        for (int rf = 0; rf < 4; rf++)
#pragma unroll
          for (int cf = 0; cf < 2; cf++)
#pragma unroll
            for (int r = 0; r < 4; r++) {
              const int grow = growbase + rf * 16 + l4 * 4 + r;
              const int gcol = gc0h + cf * 16 + l15;
              const float v = acc[rf][cf][r];
              const bool ex = dPos ? (gcol == grow) : (gcol == grow + BS);
              if (dPos && gcol == grow) ws_pos[grow] = v;  // sim_pos * log2e
              rowsum[rf * 4 + r] += ex ? 0.f : EXP2F(v);
            }
      }
    }
  };

  // prologue: fill buffers 0,1 (8 loads in flight)
  stage(lds, 0);
  stage(lds + TILE_B, 1);

  int cur = 0, st = 2;
  for (int t = 0; t < NTILES - 1; ++t) {
    // wait for stage(t) only: in flight = stage(t) + stage(t+1) = 8 loads
    asm volatile("s_waitcnt vmcnt(4)" ::: "memory");
    __builtin_amdgcn_s_barrier();
    __builtin_amdgcn_sched_barrier(0);
    if (t + 2 < NTILES) stage(lds + st * TILE_B, t + 2);
    compute(lds + cur * TILE_B, col0 + t * BN);
    cur = (cur + 1 == 3) ? 0 : cur + 1;
    st = (st + 1 == 3) ? 0 : st + 1;
  }
  asm volatile("s_waitcnt vmcnt(0)" ::: "memory");
  __builtin_amdgcn_s_barrier();
  __builtin_amdgcn_sched_barrier(0);
  compute(lds + cur * TILE_B, col0 + (NTILES - 1) * BN);

  // reduce across the 16 lanes (l15) sharing each row
#pragma unroll
  for (int s = 0; s < 16; s++) {
    float v = rowsum[s];
    v += __shfl_xor(v, 1, 64);
    v += __shfl_xor(v, 2, 64);
    v += __shfl_xor(v, 4, 64);
    v += __shfl_xor(v, 8, 64);
    rowsum[s] = v;
  }
  if (l15 == 0) {
    float* dst = ws_neg + (size_t)nb * BS + growbase;
#pragma unroll
    for (int rf = 0; rf < 4; rf++)
#pragma unroll
      for (int r = 0; r < 4; r++) dst[rf * 16 + l4 * 4 + r] = rowsum[rf * 4 + r];
  }
}

// Kernel 3a: per-row loss, 32-block partial sums.
__global__ __launch_bounds__(256) void finalize1(const float* __restrict__ ws_neg,
                                                 const float* __restrict__ ws_pos,
                                                 float* __restrict__ partial) {
  const int row = blockIdx.x * 256 + threadIdx.x;
  float neg = 0.f;
#pragma unroll
  for (int p = 0; p < NPART; p++) neg += ws_neg[(size_t)p * BS + row];
  // loss = log(neg_sum + eps) - sim_pos ; sim_pos = (sim*log2e)*ln2
  float local = logf(neg + 1e-6f) - ws_pos[row] * LN2F;
#pragma unroll
  for (int m = 1; m <= 32; m <<= 1) local += __shfl_xor(local, m, 64);
  __shared__ float red[4];
  if ((threadIdx.x & 63) == 0) red[threadIdx.x >> 6] = local;
  __syncthreads();
  if (threadIdx.x == 0) partial[blockIdx.x] = red[0] + red[1] + red[2] + red[3];
}

// Kernel 3b: final mean over the 32 block partials.
__global__ void finalize2(const float* __restrict__ partial, float* __restrict__ out) {
  float v = ((int)threadIdx.x < 32) ? partial[threadIdx.x] : 0.f;
#pragma unroll
  for (int m = 1; m <= 32; m <<= 1) v += __shfl_xor(v, m, 64);
  if (threadIdx.x == 0) out[0] = v * (1.f / BS);
}

extern "C" void kernel_launch(void* const* d_in, const int* in_sizes, int n_in,
                              void* d_out, int out_size, void* d_ws, size_t ws_size,
                              hipStream_t stream) {
  const float* f = (const float*)d_in[0];
  const float* noise = (const float*)d_in[1];
  char* ws = (char*)d_ws;
  __hip_bfloat16* catb = (__hip_bfloat16*)ws;                 // 4 MiB
  float* ws_pos = (float*)(ws + (size_t)NROWS * D * 2);       // 32 KiB
  float* ws_neg = ws_pos + BS;                                // 1 MiB
  float* partial = ws_neg + (size_t)NPART * BS;               // 128 B

  nrm_cvt<<<NROWS / 4, 256, 0, stream>>>(f, noise, catb);
  dim3 grid(NSPLIT, BS / BM);                                 // 32 x 32 = 1024 blocks
  infonce_main<<<grid, 256, 0, stream>>>(catb, ws_neg, ws_pos);
  finalize1<<<BS / 256, 256, 0, stream>>>(ws_neg, ws_pos, partial);
  finalize2<<<1, 64, 0, stream>>>(partial, (float*)d_out);
}

// Round 4
// 54.777 us; speedup vs baseline: 1.7721x; 1.0150x over previous
//
#include <hip/hip_runtime.h>
#include <hip/hip_bf16.h>
#include <math.h>

#define BS 8192
#define D 128
#define NROWS 16384               // 2*BS
#define BM 256                    // rows per block = 4 waves x 64
#define BN 64                     // cols per tile
#define COLS_PER_BLOCK 512
#define NTILES (COLS_PER_BLOCK / BN)      // 8
#define NSPLIT (NROWS / COLS_PER_BLOCK)   // 32
#define NPART NSPLIT                      // 32 partial buffers
#define TILE_B (BN * 256)                 // 16 KiB per LDS buffer

typedef __bf16 bf16x8 __attribute__((ext_vector_type(8)));
typedef float f32x4 __attribute__((ext_vector_type(4)));

#define SQRT_LOG2E 1.2011224087864498f
#define LN2F 0.6931471805599453f

#if __has_builtin(__builtin_amdgcn_exp2f)
#define EXP2F(x) __builtin_amdgcn_exp2f(x)
#else
#define EXP2F(x) exp2f(x)
#endif

__device__ __forceinline__ void gload_lds16(const void* g, void* l) {
  __builtin_amdgcn_global_load_lds(
      (const __attribute__((address_space(1))) void*)g,
      (__attribute__((address_space(3))) void*)l, 16, 0, 0);
}

// Kernel 1: row norms + pre-scaled bf16 conversion.
// cat rows [0,8192) = noise, [8192,16384) = f. Rows scaled by sqrt(log2e)/||row||
// so the MFMA dot yields cos_sim * log2(e) -> epilogue is a bare v_exp.
__global__ __launch_bounds__(256) void nrm_cvt(const float* __restrict__ f,
                                               const float* __restrict__ noise,
                                               __hip_bfloat16* __restrict__ catb) {
  const int lane = threadIdx.x & 63;
  const int wv = threadIdx.x >> 6;
  const int row = blockIdx.x * 4 + wv;
  const float* src = (row < BS) ? (noise + (size_t)row * D) : (f + (size_t)(row - BS) * D);
  float2 v = ((const float2*)src)[lane];
  float ss = v.x * v.x + v.y * v.y;
#pragma unroll
  for (int m = 1; m <= 32; m <<= 1) ss += __shfl_xor(ss, m, 64);
  float s = SQRT_LOG2E / sqrtf(ss);
  float2 sv;
  sv.x = v.x * s;
  sv.y = v.y * s;
  __hip_bfloat162 b2 = __float22bfloat162_rn(sv);
  ((__hip_bfloat162*)(catb + (size_t)row * D))[lane] = b2;
}

// Kernel 2: fused GEMM + exp2 + row-sum. 4 waves x 64 rows, shared 64-col B tiles.
// Triple-buffered LDS staged via global_load_lds (pre-swizzled source), counted
// vmcnt(4) + one raw s_barrier per tile -> no vmcnt(0) drain in the main loop.
// NOTE: no min-waves clause — (256,3) forced VGPR=84 and spilled (WRITE_SIZE 23.8MB).
__global__ __launch_bounds__(256) void infonce_main(
    const __hip_bfloat16* __restrict__ catb,
    float* __restrict__ ws_neg, float* __restrict__ ws_pos) {
  __shared__ __align__(16) char lds[3 * TILE_B];  // 48 KiB -> 3 blocks/CU
  const int tid = threadIdx.x;
  const int lane = tid & 63;
  const int w = tid >> 6;
  const int l15 = lane & 15, l4 = lane >> 4;
  const int nb = blockIdx.x, mb = blockIdx.y;
  const int mrow0 = mb * BM;
  const int col0 = nb * COLS_PER_BLOCK;
  const int growbase = mrow0 + w * 64;
  const char* catbytes = (const char*)catb;

  // staging constants: thread stages cols {i*16 + (tid>>4)}, 16B k-chunk (tid&15),
  // source pre-swizzled (XOR with (col&7)) so LDS dest stays linear.
  const int c16 = tid >> 4;
  const int kswz = ((tid & 15) ^ (c16 & 7)) << 4;
  const int ldst = c16 * 256 + (tid & 15) * 16;

  auto stage = [&](char* buf, int t) {
    const char* gb = catbytes + (size_t)(col0 + t * BN) * 256;
#pragma unroll
    for (int i = 0; i < 4; i++) {
      gload_lds16(gb + (i * 16 + c16) * 256 + kswz, buf + i * 4096 + ldst);
    }
  };

  // A fragments: this wave's 64 f-rows, all of K=128 (64 VGPRs).
  bf16x8 a[4][4];
  {
    const char* fb = catbytes + (size_t)BS * 256;
#pragma unroll
    for (int rf = 0; rf < 4; rf++) {
      const char* p = fb + (size_t)(growbase + rf * 16 + l15) * 256 + l4 * 16;
#pragma unroll
      for (int kk = 0; kk < 4; kk++) a[rf][kk] = *(const bf16x8*)(p + kk * 64);
    }
  }

  // ds_read swizzled k offsets (col&7 == l15&7 for all cf/h)
  int koff[4];
#pragma unroll
  for (int kk = 0; kk < 4; kk++) koff[kk] = ((kk * 64 + l4 * 16) ^ ((l15 & 7) << 4));

  float rowsum[16];
#pragma unroll
  for (int i = 0; i < 16; i++) rowsum[i] = 0.f;

  auto compute = [&](const char* buf, int colT) {
#pragma unroll
    for (int h = 0; h < 2; h++) {
      f32x4 acc[4][2];
      const f32x4 z = {0.f, 0.f, 0.f, 0.f};
#pragma unroll
      for (int rf = 0; rf < 4; rf++) {
        acc[rf][0] = z;
        acc[rf][1] = z;
      }
#pragma unroll
      for (int kk = 0; kk < 4; kk++) {
        bf16x8 b0 = *(const bf16x8*)(buf + (h * 32 + l15) * 256 + koff[kk]);
        bf16x8 b1 = *(const bf16x8*)(buf + (h * 32 + 16 + l15) * 256 + koff[kk]);
#pragma unroll
        for (int rf = 0; rf < 4; rf++) {
          acc[rf][0] = __builtin_amdgcn_mfma_f32_16x16x32_bf16(a[rf][kk], b0, acc[rf][0], 0, 0, 0);
          acc[rf][1] = __builtin_amdgcn_mfma_f32_16x16x32_bf16(a[rf][kk], b1, acc[rf][1], 0, 0, 0);
        }
      }
      // epilogue: acc = sim*log2e -> exp2, accumulate row sums, excise diagonals.
      const int gc0h = colT + h * 32;
      const bool dPos = ((gc0h >> 6) == (growbase >> 6));
      const bool dSelf = (gc0h >= BS) && (((gc0h - BS) >> 6) == (growbase >> 6));
      if (!dPos && !dSelf) {
#pragma unroll
        for (int rf = 0; rf < 4; rf++)
#pragma unroll
          for (int cf = 0; cf < 2; cf++)
#pragma unroll
            for (int r = 0; r < 4; r++) rowsum[rf * 4 + r] += EXP2F(acc[rf][cf][r]);
      } else {
#pragma unroll
        for (int rf = 0; rf < 4; rf++)
#pragma unroll
          for (int cf = 0; cf < 2; cf++)
#pragma unroll
            for (int r = 0; r < 4; r++) {
              const int grow = growbase + rf * 16 + l4 * 4 + r;
              const int gcol = gc0h + cf * 16 + l15;
              const float v = acc[rf][cf][r];
              const bool ex = dPos ? (gcol == grow) : (gcol == grow + BS);
              if (dPos && gcol == grow) ws_pos[grow] = v;  // sim_pos * log2e
              rowsum[rf * 4 + r] += ex ? 0.f : EXP2F(v);
            }
      }
    }
  };

  // prologue: fill buffers 0,1 (8 loads in flight)
  stage(lds, 0);
  stage(lds + TILE_B, 1);

  int cur = 0, st = 2;
  for (int t = 0; t < NTILES - 1; ++t) {
    // wait for stage(t) only: in flight = stage(t) + stage(t+1) = 8 loads
    asm volatile("s_waitcnt vmcnt(4)" ::: "memory");
    __builtin_amdgcn_s_barrier();
    __builtin_amdgcn_sched_barrier(0);
    if (t + 2 < NTILES) stage(lds + st * TILE_B, t + 2);
    compute(lds + cur * TILE_B, col0 + t * BN);
    cur = (cur + 1 == 3) ? 0 : cur + 1;
    st = (st + 1 == 3) ? 0 : st + 1;
  }
  asm volatile("s_waitcnt vmcnt(0)" ::: "memory");
  __builtin_amdgcn_s_barrier();
  __builtin_amdgcn_sched_barrier(0);
  compute(lds + cur * TILE_B, col0 + (NTILES - 1) * BN);

  // reduce across the 16 lanes (l15) sharing each row
#pragma unroll
  for (int s = 0; s < 16; s++) {
    float v = rowsum[s];
    v += __shfl_xor(v, 1, 64);
    v += __shfl_xor(v, 2, 64);
    v += __shfl_xor(v, 4, 64);
    v += __shfl_xor(v, 8, 64);
    rowsum[s] = v;
  }
  if (l15 == 0) {
    float* dst = ws_neg + (size_t)nb * BS + growbase;
#pragma unroll
    for (int rf = 0; rf < 4; rf++)
#pragma unroll
      for (int r = 0; r < 4; r++) dst[rf * 16 + l4 * 4 + r] = rowsum[rf * 4 + r];
  }
}

// Kernel 3a: per-row loss, 32-block partial sums.
__global__ __launch_bounds__(256) void finalize1(const float* __restrict__ ws_neg,
                                                 const float* __restrict__ ws_pos,
                                                 float* __restrict__ partial) {
  const int row = blockIdx.x * 256 + threadIdx.x;
  float neg = 0.f;
#pragma unroll
  for (int p = 0; p < NPART; p++) neg += ws_neg[(size_t)p * BS + row];
  // loss = log(neg_sum + eps) - sim_pos ; sim_pos = (sim*log2e)*ln2
  float local = logf(neg + 1e-6f) - ws_pos[row] * LN2F;
#pragma unroll
  for (int m = 1; m <= 32; m <<= 1) local += __shfl_xor(local, m, 64);
  __shared__ float red[4];
  if ((threadIdx.x & 63) == 0) red[threadIdx.x >> 6] = local;
  __syncthreads();
  if (threadIdx.x == 0) partial[blockIdx.x] = red[0] + red[1] + red[2] + red[3];
}

// Kernel 3b: final mean over the 32 block partials.
__global__ void finalize2(const float* __restrict__ partial, float* __restrict__ out) {
  float v = ((int)threadIdx.x < 32) ? partial[threadIdx.x] : 0.f;
#pragma unroll
  for (int m = 1; m <= 32; m <<= 1) v += __shfl_xor(v, m, 64);
  if (threadIdx.x == 0) out[0] = v * (1.f / BS);
}

extern "C" void kernel_launch(void* const* d_in, const int* in_sizes, int n_in,
                              void* d_out, int out_size, void* d_ws, size_t ws_size,
                              hipStream_t stream) {
  const float* f = (const float*)d_in[0];
  const float* noise = (const float*)d_in[1];
  char* ws = (char*)d_ws;
  __hip_bfloat16* catb = (__hip_bfloat16*)ws;                 // 4 MiB
  float* ws_pos = (float*)(ws + (size_t)NROWS * D * 2);       // 32 KiB
  float* ws_neg = ws_pos + BS;                                // 1 MiB
  float* partial = ws_neg + (size_t)NPART * BS;               // 128 B

  nrm_cvt<<<NROWS / 4, 256, 0, stream>>>(f, noise, catb);
  dim3 grid(NSPLIT, BS / BM);                                 // 32 x 32 = 1024 blocks
  infonce_main<<<grid, 256, 0, stream>>>(catb, ws_neg, ws_pos);
  finalize1<<<BS / 256, 256, 0, stream>>>(ws_neg, ws_pos, partial);
  finalize2<<<1, 64, 0, stream>>>(partial, (float*)d_out);
}

// Round 5
// 54.354 us; speedup vs baseline: 1.7859x; 1.0078x over previous
//
#include <hip/hip_runtime.h>
#include <hip/hip_bf16.h>
#include <math.h>

#define BS 8192
#define D 128
#define NROWS 16384               // 2*BS
#define BM 256                    // rows per block = 4 waves x 64
#define BN 64                     // cols per tile
#define COLS_PER_BLOCK 512
#define NTILES (COLS_PER_BLOCK / BN)      // 8
#define NSPLIT (NROWS / COLS_PER_BLOCK)   // 32
#define NPART NSPLIT                      // 32 partial buffers
#define TILE_B (BN * 256)                 // 16 KiB per LDS buffer

typedef __bf16 bf16x8 __attribute__((ext_vector_type(8)));
typedef float f32x4 __attribute__((ext_vector_type(4)));

#define SQRT_LOG2E 1.2011224087864498f
#define LN2F 0.6931471805599453f

#if __has_builtin(__builtin_amdgcn_exp2f)
#define EXP2F(x) __builtin_amdgcn_exp2f(x)
#else
#define EXP2F(x) exp2f(x)
#endif

__device__ __forceinline__ void gload_lds16(const void* g, void* l) {
  __builtin_amdgcn_global_load_lds(
      (const __attribute__((address_space(1))) void*)g,
      (__attribute__((address_space(3))) void*)l, 16, 0, 0);
}

// Kernel 1: row norms + pre-scaled bf16 conversion.
// cat rows [0,8192) = noise, [8192,16384) = f. Rows scaled by sqrt(log2e)/||row||
// so the MFMA dot yields cos_sim * log2(e) -> epilogue is a bare v_exp.
__global__ __launch_bounds__(256) void nrm_cvt(const float* __restrict__ f,
                                               const float* __restrict__ noise,
                                               __hip_bfloat16* __restrict__ catb) {
  const int lane = threadIdx.x & 63;
  const int wv = threadIdx.x >> 6;
  const int row = blockIdx.x * 4 + wv;
  const float* src = (row < BS) ? (noise + (size_t)row * D) : (f + (size_t)(row - BS) * D);
  float2 v = ((const float2*)src)[lane];
  float ss = v.x * v.x + v.y * v.y;
#pragma unroll
  for (int m = 1; m <= 32; m <<= 1) ss += __shfl_xor(ss, m, 64);
  float s = SQRT_LOG2E / sqrtf(ss);
  float2 sv;
  sv.x = v.x * s;
  sv.y = v.y * s;
  __hip_bfloat162 b2 = __float22bfloat162_rn(sv);
  ((__hip_bfloat162*)(catb + (size_t)row * D))[lane] = b2;
}

// Kernel 2: fused GEMM + exp2 + row-sum. 4 waves x 64 rows, shared 64-col B tiles.
// Double-buffered 32 KiB LDS (4 blocks/CU resident, grid exactly 4/CU) staged via
// global_load_lds with pre-swizzled source; one vmcnt wait + s_barrier per tile.
// NOTE: no min-waves clause — (256,3) forced VGPR=84 and spilled (WRITE_SIZE 23.8MB).
__global__ __launch_bounds__(256) void infonce_main(
    const __hip_bfloat16* __restrict__ catb,
    float* __restrict__ ws_neg, float* __restrict__ ws_pos) {
  __shared__ __align__(16) char lds[2 * TILE_B];  // 32 KiB -> 4 blocks/CU
  const int tid = threadIdx.x;
  const int lane = tid & 63;
  const int w = tid >> 6;
  const int l15 = lane & 15, l4 = lane >> 4;
  const int nb = blockIdx.x, mb = blockIdx.y;
  const int mrow0 = mb * BM;
  const int col0 = nb * COLS_PER_BLOCK;
  const int growbase = mrow0 + w * 64;
  const char* catbytes = (const char*)catb;

  // staging constants: thread stages cols {i*16 + (tid>>4)}, 16B k-chunk (tid&15),
  // source pre-swizzled (XOR with (col&7)) so LDS dest stays linear.
  const int c16 = tid >> 4;
  const int kswz = ((tid & 15) ^ (c16 & 7)) << 4;
  const int ldst = c16 * 256 + (tid & 15) * 16;

  auto stage = [&](char* buf, int t) {
    const char* gb = catbytes + (size_t)(col0 + t * BN) * 256;
#pragma unroll
    for (int i = 0; i < 4; i++) {
      gload_lds16(gb + (i * 16 + c16) * 256 + kswz, buf + i * 4096 + ldst);
    }
  };

  // start tile-0 DMA before the A-fragment loads so L2 latency overlaps
  stage(lds, 0);

  // A fragments: this wave's 64 f-rows, all of K=128 (64 VGPRs).
  bf16x8 a[4][4];
  {
    const char* fb = catbytes + (size_t)BS * 256;
#pragma unroll
    for (int rf = 0; rf < 4; rf++) {
      const char* p = fb + (size_t)(growbase + rf * 16 + l15) * 256 + l4 * 16;
#pragma unroll
      for (int kk = 0; kk < 4; kk++) a[rf][kk] = *(const bf16x8*)(p + kk * 64);
    }
  }

  // ds_read swizzled k offsets (col&7 == l15&7 for all cf/h)
  int koff[4];
#pragma unroll
  for (int kk = 0; kk < 4; kk++) koff[kk] = ((kk * 64 + l4 * 16) ^ ((l15 & 7) << 4));

  float rowsum[16];
#pragma unroll
  for (int i = 0; i < 16; i++) rowsum[i] = 0.f;

  auto compute = [&](const char* buf, int colT) {
#pragma unroll
    for (int h = 0; h < 2; h++) {
      f32x4 acc[4][2];
      const f32x4 z = {0.f, 0.f, 0.f, 0.f};
#pragma unroll
      for (int rf = 0; rf < 4; rf++) {
        acc[rf][0] = z;
        acc[rf][1] = z;
      }
#pragma unroll
      for (int kk = 0; kk < 4; kk++) {
        bf16x8 b0 = *(const bf16x8*)(buf + (h * 32 + l15) * 256 + koff[kk]);
        bf16x8 b1 = *(const bf16x8*)(buf + (h * 32 + 16 + l15) * 256 + koff[kk]);
#pragma unroll
        for (int rf = 0; rf < 4; rf++) {
          acc[rf][0] = __builtin_amdgcn_mfma_f32_16x16x32_bf16(a[rf][kk], b0, acc[rf][0], 0, 0, 0);
          acc[rf][1] = __builtin_amdgcn_mfma_f32_16x16x32_bf16(a[rf][kk], b1, acc[rf][1], 0, 0, 0);
        }
      }
      // epilogue: acc = sim*log2e -> exp2, accumulate row sums, excise diagonals.
      const int gc0h = colT + h * 32;
      const bool dPos = ((gc0h >> 6) == (growbase >> 6));
      const bool dSelf = (gc0h >= BS) && (((gc0h - BS) >> 6) == (growbase >> 6));
      if (!dPos && !dSelf) {
#pragma unroll
        for (int rf = 0; rf < 4; rf++)
#pragma unroll
          for (int cf = 0; cf < 2; cf++)
#pragma unroll
            for (int r = 0; r < 4; r++) rowsum[rf * 4 + r] += EXP2F(acc[rf][cf][r]);
      } else {
#pragma unroll
        for (int rf = 0; rf < 4; rf++)
#pragma unroll
          for (int cf = 0; cf < 2; cf++)
#pragma unroll
            for (int r = 0; r < 4; r++) {
              const int grow = growbase + rf * 16 + l4 * 4 + r;
              const int gcol = gc0h + cf * 16 + l15;
              const float v = acc[rf][cf][r];
              const bool ex = dPos ? (gcol == grow) : (gcol == grow + BS);
              if (dPos && gcol == grow) ws_pos[grow] = v;  // sim_pos * log2e
              rowsum[rf * 4 + r] += ex ? 0.f : EXP2F(v);
            }
      }
    }
  };

  // double-buffer main loop: wait stage(t), barrier, issue stage(t+1), compute(t).
  // stage(t+1) overwrites the buffer all waves finished reading before this barrier.
  int cur = 0;
  for (int t = 0; t < NTILES; ++t) {
    asm volatile("s_waitcnt vmcnt(0)" ::: "memory");
    __builtin_amdgcn_s_barrier();
    __builtin_amdgcn_sched_barrier(0);
    if (t + 1 < NTILES) stage(lds + (cur ^ 1) * TILE_B, t + 1);
    compute(lds + cur * TILE_B, col0 + t * BN);
    cur ^= 1;
  }

  // reduce across the 16 lanes (l15) sharing each row
#pragma unroll
  for (int s = 0; s < 16; s++) {
    float v = rowsum[s];
    v += __shfl_xor(v, 1, 64);
    v += __shfl_xor(v, 2, 64);
    v += __shfl_xor(v, 4, 64);
    v += __shfl_xor(v, 8, 64);
    rowsum[s] = v;
  }
  if (l15 == 0) {
    float* dst = ws_neg + (size_t)nb * BS + growbase;
#pragma unroll
    for (int rf = 0; rf < 4; rf++)
#pragma unroll
      for (int r = 0; r < 4; r++) dst[rf * 16 + l4 * 4 + r] = rowsum[rf * 4 + r];
  }
}

// Kernel 3a: per-row loss, 32-block partial sums.
__global__ __launch_bounds__(256) void finalize1(const float* __restrict__ ws_neg,
                                                 const float* __restrict__ ws_pos,
                                                 float* __restrict__ partial) {
  const int row = blockIdx.x * 256 + threadIdx.x;
  float neg = 0.f;
#pragma unroll
  for (int p = 0; p < NPART; p++) neg += ws_neg[(size_t)p * BS + row];
  // loss = log(neg_sum + eps) - sim_pos ; sim_pos = (sim*log2e)*ln2
  float local = logf(neg + 1e-6f) - ws_pos[row] * LN2F;
#pragma unroll
  for (int m = 1; m <= 32; m <<= 1) local += __shfl_xor(local, m, 64);
  __shared__ float red[4];
  if ((threadIdx.x & 63) == 0) red[threadIdx.x >> 6] = local;
  __syncthreads();
  if (threadIdx.x == 0) partial[blockIdx.x] = red[0] + red[1] + red[2] + red[3];
}

// Kernel 3b: final mean over the 32 block partials.
__global__ void finalize2(const float* __restrict__ partial, float* __restrict__ out) {
  float v = ((int)threadIdx.x < 32) ? partial[threadIdx.x] : 0.f;
#pragma unroll
  for (int m = 1; m <= 32; m <<= 1) v += __shfl_xor(v, m, 64);
  if (threadIdx.x == 0) out[0] = v * (1.f / BS);
}

extern "C" void kernel_launch(void* const* d_in, const int* in_sizes, int n_in,
                              void* d_out, int out_size, void* d_ws, size_t ws_size,
                              hipStream_t stream) {
  const float* f = (const float*)d_in[0];
  const float* noise = (const float*)d_in[1];
  char* ws = (char*)d_ws;
  __hip_bfloat16* catb = (__hip_bfloat16*)ws;                 // 4 MiB
  float* ws_pos = (float*)(ws + (size_t)NROWS * D * 2);       // 32 KiB
  float* ws_neg = ws_pos + BS;                                // 1 MiB
  float* partial = ws_neg + (size_t)NPART * BS;               // 128 B

  nrm_cvt<<<NROWS / 4, 256, 0, stream>>>(f, noise, catb);
  dim3 grid(NSPLIT, BS / BM);                                 // 32 x 32 = 1024 blocks
  infonce_main<<<grid, 256, 0, stream>>>(catb, ws_neg, ws_pos);
  finalize1<<<BS / 256, 256, 0, stream>>>(ws_neg, ws_pos, partial);
  finalize2<<<1, 64, 0, stream>>>(partial, (float*)d_out);
}